// Round 1
// baseline (25406.442 us; speedup 1.0000x reference)
//
#include <hip/hip_runtime.h>
#include <cstdint>
#include <cstddef>

#define L_ 128
#define B_ 32
#define E_ 512
#define H_ 512
#define H2_ 1024
#define V_ 32000
#define SOS_ 65

typedef __attribute__((ext_vector_type(8))) short bf8;
typedef __attribute__((ext_vector_type(4))) float f4;

__device__ __forceinline__ short bf1(float x){
  union { float f; unsigned u; } c; c.f = x;
  return (short)((c.u + 0x8000u) >> 16);
}
__device__ __forceinline__ bf8 fragf(const float* p){
  f4 a = ((const f4*)p)[0], b = ((const f4*)p)[1];
  bf8 r;
  r[0]=bf1(a[0]); r[1]=bf1(a[1]); r[2]=bf1(a[2]); r[3]=bf1(a[3]);
  r[4]=bf1(b[0]); r[5]=bf1(b[1]); r[6]=bf1(b[2]); r[7]=bf1(b[3]);
  return r;
}
__device__ __forceinline__ float sigf(float x){ return 1.0f/(1.0f + __expf(-x)); }
__device__ __forceinline__ float tanh_(float x){ return 1.0f - 2.0f/(__expf(2.0f*x)+1.0f); }
__device__ __forceinline__ f4 mfma16(bf8 a, bf8 b, f4 c){
  return __builtin_amdgcn_mfma_f32_16x16x32_bf16(a, b, c, 0, 0, 0);
}

// ---------------- init ----------------
__global__ __launch_bounds__(256) void k_init(float* __restrict__ ws,
                                              int* __restrict__ inp,
                                              float* __restrict__ loss)
{
  int gid = blockIdx.x*256 + threadIdx.x;
  if (gid < 131072) ws[gid] = 0.f;   // hf,cf,hb,cb,h_d,c_d contiguous
  if (gid < 32) inp[gid] = SOS_;
  if (gid == 0) *loss = 0.f;
}

// ---------------- optional W_out bf16 prepack ----------------
__global__ __launch_bounds__(256) void k_pack(const float* __restrict__ W,
                                              short* __restrict__ out)
{
  size_t gid = (size_t)blockIdx.x*256 + threadIdx.x;  // < V_*H2_/8
  ((bf8*)out)[gid] = fragf(W + gid*8);
}

// ---------------- encoder gates GEMM (both dirs), K-split 4 ----------------
// gparts layout: [ks][dir][32][2048]
__global__ __launch_bounds__(256) void k_enc_gates(
    const int* __restrict__ x, int t, const float* __restrict__ emb_enc,
    const float* __restrict__ Wih_f, const float* __restrict__ Whh_f,
    const float* __restrict__ Wih_b, const float* __restrict__ Whh_b,
    const float* __restrict__ hf, const float* __restrict__ hb,
    float* __restrict__ gparts)
{
  const int tid = threadIdx.x;
  const int wave = tid >> 6, lane = tid & 63;
  const int q = lane >> 4, col = lane & 15, kq = q*8;
  const int nt = blockIdx.x, ks = blockIdx.y, dir = blockIdx.z;
  const int n = nt*64 + wave*16 + col;
  const bool inE = (ks < 2);
  const int kbase = ks*256;
  const float* W = inE ? (dir ? Wih_b : Wih_f) : (dir ? Whh_b : Whh_f);
  const int kloc = inE ? kbase : (kbase - 512);
  const float *a0, *a1;
  if (inE) {
    a0 = emb_enc + (size_t)x[col*L_ + t]*E_ + kloc + kq;
    a1 = emb_enc + (size_t)x[(16+col)*L_ + t]*E_ + kloc + kq;
  } else {
    const float* hs = dir ? hb : hf;
    a0 = hs + col*H_ + kloc + kq;
    a1 = hs + (16+col)*H_ + kloc + kq;
  }
  const float* bp = W + (size_t)n*512 + kloc + kq;
  f4 acc0 = {0.f,0.f,0.f,0.f}, acc1 = {0.f,0.f,0.f,0.f};
#pragma unroll
  for (int i = 0; i < 8; ++i) {
    bf8 bb  = fragf(bp + i*32);
    bf8 af0 = fragf(a0 + i*32);
    bf8 af1 = fragf(a1 + i*32);
    acc0 = mfma16(af0, bb, acc0);
    acc1 = mfma16(af1, bb, acc1);
  }
  float* out = gparts + (size_t)((ks*2 + dir)*B_)*2048;
#pragma unroll
  for (int r = 0; r < 4; ++r) {
    out[(size_t)(4*q + r)*2048 + n]      = acc0[r];
    out[(size_t)(16 + 4*q + r)*2048 + n] = acc1[r];
  }
}

// ---------------- encoder cell (pointwise, both dirs) ----------------
__global__ __launch_bounds__(256) void k_enc_cell(
    const float* __restrict__ gparts,
    const float* __restrict__ bih_f, const float* __restrict__ bhh_f,
    const float* __restrict__ bih_b, const float* __restrict__ bhh_b,
    float* __restrict__ hf, float* __restrict__ cf,
    float* __restrict__ hb, float* __restrict__ cb,
    float* __restrict__ EO, int t)
{
  int gid = blockIdx.x*256 + threadIdx.x;      // < 32768
  int dir = gid >> 14, b = (gid >> 9) & 31, j = gid & 511;
  const float* bi = dir ? bih_b : bih_f;
  const float* bh = dir ? bhh_b : bhh_f;
  float g[4];
#pragma unroll
  for (int gt = 0; gt < 4; ++gt) {
    int n = gt*H_ + j;
    float s = bi[n] + bh[n];
#pragma unroll
    for (int ks = 0; ks < 4; ++ks)
      s += gparts[(size_t)((ks*2 + dir)*B_ + b)*2048 + n];
    g[gt] = s;
  }
  float* c = dir ? cb : cf;
  float* h = dir ? hb : hf;
  float cp = c[b*H_ + j];
  float cn = sigf(g[1])*cp + sigf(g[0])*tanh_(g[2]);
  float hn = sigf(g[3])*tanh_(cn);
  c[b*H_ + j] = cn;
  h[b*H_ + j] = hn;
  if (b == 0) EO[t*H2_ + dir*H_ + j] = hn;   // faithful source-bug broadcast
}

// ---------------- decoder attention: scores+softmax+ctx, one block per b ----
__global__ __launch_bounds__(256) void k_attn(
    const int* __restrict__ inp, const float* __restrict__ emb_dec,
    const float* __restrict__ h_d, const float* __restrict__ W_attn,
    const float* __restrict__ b_attn, const float* __restrict__ EO,
    float* __restrict__ ctx)
{
  __shared__ float X[2048];
  __shared__ float sc[128];
  __shared__ float red[8];
  const int b = blockIdx.x, tid = threadIdx.x;
  const int row = inp[b];
  ((f4*)X)[tid]          = ((const f4*)(emb_dec + (size_t)row*H2_))[tid];
  ((f4*)(X + 1024))[tid] = ((const f4*)(h_d + (size_t)b*H2_))[tid];
  __syncthreads();
  const int lg = tid >> 4, kl = tid & 15;
#pragma unroll
  for (int lr = 0; lr < 8; ++lr) {
    const int l = lr*16 + lg;
    const float* w = W_attn + (size_t)l*2048;
    float s = 0.f;
    for (int kk = kl*4; kk < 2048; kk += 64) {
      f4 wv = *(const f4*)(w + kk);
      f4 xv = *(const f4*)(X + kk);
      s += wv[0]*xv[0] + wv[1]*xv[1] + wv[2]*xv[2] + wv[3]*xv[3];
    }
#pragma unroll
    for (int msk = 1; msk < 16; msk <<= 1) s += __shfl_xor(s, msk);
    if (kl == 0) sc[l] = s + b_attn[l];
  }
  __syncthreads();
  const float v = sc[tid & 127];
  float m_ = v;
#pragma unroll
  for (int msk = 1; msk < 64; msk <<= 1) m_ = fmaxf(m_, __shfl_xor(m_, msk));
  if ((tid & 63) == 0) red[tid >> 6] = m_;
  __syncthreads();
  const float M = fmaxf(fmaxf(red[0], red[1]), fmaxf(red[2], red[3]));
  const float e_ = __expf(v - M);
  float s_ = e_;
#pragma unroll
  for (int msk = 1; msk < 64; msk <<= 1) s_ += __shfl_xor(s_, msk);
  if ((tid & 63) == 0) red[4 + (tid >> 6)] = s_;
  __syncthreads();
  const float S = red[4] + red[5];
  if (tid < 128) sc[tid] = e_ / S;
  __syncthreads();
  const int d0 = tid*4;
  f4 a = {0.f,0.f,0.f,0.f};
  for (int l = 0; l < 128; ++l) {
    const float wgt = sc[l];
    const f4 ev = *(const f4*)(EO + (size_t)l*H2_ + d0);
    a[0] += wgt*ev[0]; a[1] += wgt*ev[1]; a[2] += wgt*ev[2]; a[3] += wgt*ev[3];
  }
  *(f4*)(ctx + (size_t)b*H2_ + d0) = a;
}

// ---------------- comb GEMM: relu(concat(e,ctx)@W_comb^T + b) ; K-split 4 ---
// cparts layout: [ks][32][1024] (bias+relu applied at consumption)
__global__ __launch_bounds__(256) void k_comb(
    const int* __restrict__ inp, const float* __restrict__ emb_dec,
    const float* __restrict__ ctx, const float* __restrict__ W_comb,
    float* __restrict__ cparts)
{
  const int tid = threadIdx.x, wave = tid>>6, lane = tid&63;
  const int q = lane>>4, col = lane&15, kq = q*8;
  const int nt = blockIdx.x, ks = blockIdx.y;
  const int n = nt*64 + wave*16 + col;
  const int kbase = ks*512;
  const bool inE = (ks < 2);
  const float *a0, *a1;
  if (inE) {
    a0 = emb_dec + (size_t)inp[col]*H2_ + kbase + kq;
    a1 = emb_dec + (size_t)inp[16+col]*H2_ + kbase + kq;
  } else {
    a0 = ctx + col*H2_ + (kbase - 1024) + kq;
    a1 = ctx + (16+col)*H2_ + (kbase - 1024) + kq;
  }
  const float* bp = W_comb + (size_t)n*2048 + kbase + kq;
  f4 acc0={0.f,0.f,0.f,0.f}, acc1={0.f,0.f,0.f,0.f};
#pragma unroll
  for (int i = 0; i < 16; ++i) {
    bf8 bb  = fragf(bp + i*32);
    bf8 af0 = fragf(a0 + i*32);
    bf8 af1 = fragf(a1 + i*32);
    acc0 = mfma16(af0, bb, acc0);
    acc1 = mfma16(af1, bb, acc1);
  }
  float* out = cparts + (size_t)(ks*B_)*H2_;
#pragma unroll
  for (int r = 0; r < 4; ++r) {
    out[(size_t)(4*q+r)*H2_ + n]    = acc0[r];
    out[(size_t)(16+4*q+r)*H2_ + n] = acc1[r];
  }
}

// comb finalize folded into A-fragment staging: relu(sum partials + bias)
__device__ __forceinline__ bf8 frag_comb(const float* cp, const float* bias){
  f4 s0 = ((const f4*)cp)[0];
  f4 s1 = ((const f4*)cp)[1];
#pragma unroll
  for (int p = 1; p < 4; ++p) {
    s0 += ((const f4*)(cp + p*(B_*H2_)))[0];
    s1 += ((const f4*)(cp + p*(B_*H2_)))[1];
  }
  s0 += ((const f4*)bias)[0];
  s1 += ((const f4*)bias)[1];
  bf8 r;
  r[0]=bf1(fmaxf(s0[0],0.f)); r[1]=bf1(fmaxf(s0[1],0.f));
  r[2]=bf1(fmaxf(s0[2],0.f)); r[3]=bf1(fmaxf(s0[3],0.f));
  r[4]=bf1(fmaxf(s1[0],0.f)); r[5]=bf1(fmaxf(s1[1],0.f));
  r[6]=bf1(fmaxf(s1[2],0.f)); r[7]=bf1(fmaxf(s1[3],0.f));
  return r;
}

// ---------------- decoder LSTM gates GEMM, K-split 4 ----------------
// gparts layout: [ks][32][4096]
__global__ __launch_bounds__(256) void k_dec_gates(
    const float* __restrict__ cparts, const float* __restrict__ b_comb,
    const float* __restrict__ h_d,
    const float* __restrict__ Wih_d, const float* __restrict__ Whh_d,
    float* __restrict__ gparts)
{
  const int tid = threadIdx.x, wave = tid>>6, lane = tid&63;
  const int q = lane>>4, col = lane&15, kq = q*8;
  const int nt = blockIdx.x, ks = blockIdx.y;
  const int n = nt*64 + wave*16 + col;
  const int kbase = ks*512;
  const bool inC = (ks < 2);
  f4 acc0={0.f,0.f,0.f,0.f}, acc1={0.f,0.f,0.f,0.f};
  if (inC) {
    const float* c0 = cparts + col*H2_ + kbase + kq;
    const float* c1 = cparts + (16+col)*H2_ + kbase + kq;
    const float* bp = Wih_d + (size_t)n*H2_ + kbase + kq;
    const float* bsp = b_comb + kbase + kq;
#pragma unroll
    for (int i = 0; i < 16; ++i) {
      bf8 bb  = fragf(bp + i*32);
      bf8 af0 = frag_comb(c0 + i*32, bsp + i*32);
      bf8 af1 = frag_comb(c1 + i*32, bsp + i*32);
      acc0 = mfma16(af0, bb, acc0);
      acc1 = mfma16(af1, bb, acc1);
    }
  } else {
    const int kh = kbase - 1024;
    const float* a0 = h_d + col*H2_ + kh + kq;
    const float* a1 = h_d + (16+col)*H2_ + kh + kq;
    const float* bp = Whh_d + (size_t)n*H2_ + kh + kq;
#pragma unroll
    for (int i = 0; i < 16; ++i) {
      bf8 bb  = fragf(bp + i*32);
      bf8 af0 = fragf(a0 + i*32);
      bf8 af1 = fragf(a1 + i*32);
      acc0 = mfma16(af0, bb, acc0);
      acc1 = mfma16(af1, bb, acc1);
    }
  }
  float* out = gparts + (size_t)(ks*B_)*4096;
#pragma unroll
  for (int r = 0; r < 4; ++r) {
    out[(size_t)(4*q+r)*4096 + n]    = acc0[r];
    out[(size_t)(16+4*q+r)*4096 + n] = acc1[r];
  }
}

// ---------------- decoder cell ----------------
__global__ __launch_bounds__(256) void k_dec_cell(
    const float* __restrict__ gparts, const float* __restrict__ bih_d,
    const float* __restrict__ bhh_d, float* __restrict__ h_d,
    float* __restrict__ c_d)
{
  int gid = blockIdx.x*256 + threadIdx.x;  // < 32768
  int b = gid >> 10, j = gid & 1023;
  float g[4];
#pragma unroll
  for (int gt = 0; gt < 4; ++gt) {
    int n = gt*H2_ + j;
    float s = bih_d[n] + bhh_d[n];
#pragma unroll
    for (int ks = 0; ks < 4; ++ks)
      s += gparts[(size_t)(ks*B_ + b)*4096 + n];
    g[gt] = s;
  }
  float cp = c_d[b*H2_ + j];
  float cn = sigf(g[1])*cp + sigf(g[0])*tanh_(g[2]);
  float hn = sigf(g[3])*tanh_(cn);
  c_d[b*H2_ + j] = cn;
  h_d[b*H2_ + j] = hn;
}

// ---------------- logits GEMM + fused per-block partial reduction -----------
template<bool PACKED>
__global__ __launch_bounds__(256) void k_logits(
    const float* __restrict__ h_d, const short* __restrict__ Wbf,
    const float* __restrict__ W_out, const float* __restrict__ b_out,
    const int* __restrict__ target, int t,
    float* __restrict__ pmax, float* __restrict__ psum,
    int* __restrict__ pidx, float* __restrict__ ptgt)
{
  __shared__ float lmax[4][32], lsum[4][32];
  __shared__ int lidx[4][32];
  const int tid = threadIdx.x, wave = tid>>6, lane = tid&63;
  const int q = lane>>4, col = lane&15, kq = q*8;
  const int nt = blockIdx.x;
  const int n = nt*64 + wave*16 + col;
  const float* a0 = h_d + col*H2_ + kq;
  const float* a1 = h_d + (16+col)*H2_ + kq;
  f4 acc[2];
  acc[0] = (f4){0.f,0.f,0.f,0.f};
  acc[1] = (f4){0.f,0.f,0.f,0.f};
  if (PACKED) {
    const short* bp = Wbf + (size_t)n*H2_ + kq;
#pragma unroll 8
    for (int i = 0; i < 32; ++i) {
      bf8 bb = *(const bf8*)(bp + i*32);
      acc[0] = mfma16(fragf(a0 + i*32), bb, acc[0]);
      acc[1] = mfma16(fragf(a1 + i*32), bb, acc[1]);
    }
  } else {
    const float* bp = W_out + (size_t)n*H2_ + kq;
#pragma unroll 4
    for (int i = 0; i < 32; ++i) {
      bf8 bb = fragf(bp + i*32);
      acc[0] = mfma16(fragf(a0 + i*32), bb, acc[0]);
      acc[1] = mfma16(fragf(a1 + i*32), bb, acc[1]);
    }
  }
  const float bias = b_out[n];
#pragma unroll
  for (int mt = 0; mt < 2; ++mt) {
    float val[4], mv[4]; int mi[4];
#pragma unroll
    for (int r = 0; r < 4; ++r) {
      val[r] = acc[mt][r] + bias;
      int b_ = mt*16 + 4*q + r;
      if (target[b_*L_ + t] == n) ptgt[b_] = val[r];
      mv[r] = val[r]; mi[r] = n;
    }
#pragma unroll
    for (int msk = 1; msk < 16; msk <<= 1) {
#pragma unroll
      for (int r = 0; r < 4; ++r) {
        float ov = __shfl_xor(mv[r], msk);
        int oi = __shfl_xor(mi[r], msk);
        if (ov > mv[r] || (ov == mv[r] && oi < mi[r])) { mv[r] = ov; mi[r] = oi; }
      }
    }
    float sv[4];
#pragma unroll
    for (int r = 0; r < 4; ++r) sv[r] = __expf(val[r] - mv[r]);
#pragma unroll
    for (int msk = 1; msk < 16; msk <<= 1) {
#pragma unroll
      for (int r = 0; r < 4; ++r) sv[r] += __shfl_xor(sv[r], msk);
    }
    if (col == 0) {
#pragma unroll
      for (int r = 0; r < 4; ++r) {
        int b_ = mt*16 + 4*q + r;
        lmax[wave][b_] = mv[r]; lsum[wave][b_] = sv[r]; lidx[wave][b_] = mi[r];
      }
    }
  }
  __syncthreads();
  if (tid < 32) {
    float M = lmax[0][tid], S = lsum[0][tid]; int I = lidx[0][tid];
#pragma unroll
    for (int w = 1; w < 4; ++w) {
      float m2 = lmax[w][tid], s2 = lsum[w][tid]; int i2 = lidx[w][tid];
      if (m2 > M) { S = s2 + S*__expf(M - m2); M = m2; I = i2; }
      else { S += s2*__expf(m2 - M); if (m2 == M && i2 < I) I = i2; }
    }
    pmax[nt*32 + tid] = M; psum[nt*32 + tid] = S; pidx[nt*32 + tid] = I;
  }
}

// ---------------- final per-row reduce: nll + argmax feedback ----------------
__device__ __forceinline__ void comb3(float& M, float& S, int& I,
                                      float m2, float s2, int i2){
  if (m2 > M) { S = s2 + S*__expf(M - m2); M = m2; I = i2; }
  else { S += s2*__expf(m2 - M); if (m2 == M && i2 < I) I = i2; }
}

__global__ __launch_bounds__(256) void k_reduce(
    const float* __restrict__ pmax, const float* __restrict__ psum,
    const int* __restrict__ pidx, const float* __restrict__ ptgt,
    float* __restrict__ loss, int* __restrict__ inp)
{
  __shared__ float sm[4], ss[4]; __shared__ int si[4];
  const int b = blockIdx.x, tid = threadIdx.x;
  float M = -3.4e38f, S = 0.f; int I = 0x7fffffff;
  for (int tl = tid; tl < 500; tl += 256)
    comb3(M, S, I, pmax[tl*32 + b], psum[tl*32 + b], pidx[tl*32 + b]);
#pragma unroll
  for (int msk = 1; msk < 64; msk <<= 1) {
    float m2 = __shfl_xor(M, msk), s2 = __shfl_xor(S, msk);
    int i2 = __shfl_xor(I, msk);
    comb3(M, S, I, m2, s2, i2);
  }
  if ((tid & 63) == 0) { sm[tid>>6] = M; ss[tid>>6] = S; si[tid>>6] = I; }
  __syncthreads();
  if (tid == 0) {
    M = sm[0]; S = ss[0]; I = si[0];
    for (int w = 1; w < 4; ++w) comb3(M, S, I, sm[w], ss[w], si[w]);
    atomicAdd(loss, (M + __logf(S) - ptgt[b]) * (1.0f/32.0f));
    inp[b] = I;
  }
}

__global__ void k_final(const float* __restrict__ loss, float* __restrict__ out)
{
  out[0] = *loss;
  out[1] = *loss * (1.0f/128.0f);
}

// ---------------- host ----------------
extern "C" void kernel_launch(void* const* d_in, const int* in_sizes, int n_in,
                              void* d_out, int out_size, void* d_ws, size_t ws_size,
                              hipStream_t stream)
{
  const int*   x       = (const int*)d_in[0];
  const int*   target  = (const int*)d_in[1];
  const float* emb_enc = (const float*)d_in[4];
  const float* Wih_f   = (const float*)d_in[5];
  const float* Whh_f   = (const float*)d_in[6];
  const float* bih_f   = (const float*)d_in[7];
  const float* bhh_f   = (const float*)d_in[8];
  const float* Wih_b   = (const float*)d_in[9];
  const float* Whh_b   = (const float*)d_in[10];
  const float* bih_b   = (const float*)d_in[11];
  const float* bhh_b   = (const float*)d_in[12];
  const float* emb_dec = (const float*)d_in[13];
  const float* W_attn  = (const float*)d_in[14];
  const float* b_attn  = (const float*)d_in[15];
  const float* W_comb  = (const float*)d_in[16];
  const float* b_comb  = (const float*)d_in[17];
  const float* Wih_d   = (const float*)d_in[18];
  const float* Whh_d   = (const float*)d_in[19];
  const float* bih_d   = (const float*)d_in[20];
  const float* bhh_d   = (const float*)d_in[21];
  const float* W_out   = (const float*)d_in[22];
  const float* b_out   = (const float*)d_in[23];

  float* ws    = (float*)d_ws;
  float* hf    = ws + 0;        // 16384
  float* cf    = ws + 16384;
  float* hb    = ws + 32768;
  float* cb    = ws + 49152;
  float* h_d   = ws + 65536;    // 32768
  float* c_d   = ws + 98304;
  float* EO    = ws + 131072;   // 128*1024
  float* ctx   = ws + 262144;   // 32768
  float* cparts= ws + 294912;   // 4*32*1024
  float* gpe   = ws + 425984;   // 4*2*32*2048
  float* gpd   = ws + 950272;   // 4*32*4096
  float* pmax  = ws + 1474560;  // 500*32
  float* psum  = ws + 1490560;
  int*   pidx  = (int*)(ws + 1506560);
  float* ptgt  = ws + 1522560;  // 32
  float* loss  = ws + 1522592;
  int*   inp   = (int*)(ws + 1522624);

  const size_t packOff  = 8ull*1024*1024;               // bytes
  const size_t packNeed = packOff + (size_t)V_*H2_*2;   // bytes
  const bool packed = (ws_size >= packNeed);
  short* Wbf = (short*)((char*)d_ws + packOff);

  float* out = (float*)d_out;

  k_init<<<512, 256, 0, stream>>>(ws, inp, loss);
  if (packed)
    k_pack<<<16000, 256, 0, stream>>>(W_out, Wbf);

  for (int t = 0; t < L_; ++t) {
    k_enc_gates<<<dim3(32,4,2), 256, 0, stream>>>(
        x, t, emb_enc, Wih_f, Whh_f, Wih_b, Whh_b, hf, hb, gpe);
    k_enc_cell<<<128, 256, 0, stream>>>(
        gpe, bih_f, bhh_f, bih_b, bhh_b, hf, cf, hb, cb, EO, t);
  }
  for (int t = 0; t < L_; ++t) {
    k_attn<<<32, 256, 0, stream>>>(inp, emb_dec, h_d, W_attn, b_attn, EO, ctx);
    k_comb<<<dim3(16,4), 256, 0, stream>>>(inp, emb_dec, ctx, W_comb, cparts);
    k_dec_gates<<<dim3(64,4), 256, 0, stream>>>(
        cparts, b_comb, h_d, Wih_d, Whh_d, gpd);
    k_dec_cell<<<128, 256, 0, stream>>>(gpd, bih_d, bhh_d, h_d, c_d);
    if (packed)
      k_logits<true><<<500, 256, 0, stream>>>(
          h_d, Wbf, W_out, b_out, target, t, pmax, psum, pidx, ptgt);
    else
      k_logits<false><<<500, 256, 0, stream>>>(
          h_d, Wbf, W_out, b_out, target, t, pmax, psum, pidx, ptgt);
    k_reduce<<<32, 256, 0, stream>>>(pmax, psum, pidx, ptgt, loss, inp);
  }
  k_final<<<1, 1, 0, stream>>>(loss, out);
}